// Round 4
// baseline (1614.705 us; speedup 1.0000x reference)
//
#include <hip/hip_runtime.h>

typedef __attribute__((ext_vector_type(8))) short short8;
typedef __attribute__((ext_vector_type(4))) float floatx4;

#define MFMA16(a, b, acc) __builtin_amdgcn_mfma_f32_16x16x32_bf16((a), (b), (acc), 0, 0, 0)

__device__ __forceinline__ float bf2f(unsigned short u) {
  union { float f; unsigned int i; } v; v.i = ((unsigned int)u) << 16; return v.f;
}
__device__ __forceinline__ unsigned short f2bf(float f) {
  union { float f; unsigned int i; } v; v.f = f;
  unsigned int r = (v.i + 0x7fffu + ((v.i >> 16) & 1u)) >> 16;
  return (unsigned short)r;
}
__device__ __forceinline__ float sigm(float x) { return 1.0f / (1.0f + __expf(-x)); }
__device__ __forceinline__ float tanh_f(float x) { return 2.0f * sigm(2.0f * x) - 1.0f; }

// write-through 2B store: no L2 allocation, lands at LLC (coherence point)
__device__ __forceinline__ void llc_store_u16(unsigned short* p, unsigned short v) {
  unsigned int v32 = v;
  asm volatile("global_store_short %0, %1, off sc0 sc1" :: "v"(p), "v"(v32) : "memory");
}

// ---------------- hierarchical checker barrier (R0-proven, verbatim) ----------------
// flags[0..255] (lines 0-15) <- every block's t0.
// 8 leaders (bid%32==0): wave0 polls its group's 32 flags -> gflags[g] (line 16+).
// root (bid 0): polls gflags[0..7] -> gen (line 32).
// everyone: t0 polls gen. ~3 serialized poll-notice hops, minimal line contention.
// Fence-free: rotating h slabs + write-through producer stores.
__device__ __forceinline__ void gridbar(unsigned int* bar, unsigned int phase) {
  __syncthreads();                     // compiler emits vmcnt(0) drain before s_barrier
  const unsigned int bid = blockIdx.x;
  const unsigned int tid = threadIdx.x;
  unsigned int* flags  = bar;          // 256 dwords
  unsigned int* gflags = bar + 256;    // 8 dwords (line 16)
  unsigned int* gen    = bar + 512;    // line 32
  if (tid == 0)
    __hip_atomic_store(&flags[bid], phase, __ATOMIC_RELAXED, __HIP_MEMORY_SCOPE_AGENT);
  asm volatile("" ::: "memory");
  if ((bid & 31u) == 0u && tid < 64) {         // leader wave
    const unsigned int g = bid >> 5;
    unsigned int v;
    do {
      v = __hip_atomic_load(&flags[g * 32 + (tid & 31)], __ATOMIC_RELAXED, __HIP_MEMORY_SCOPE_AGENT);
      if (v < phase) __builtin_amdgcn_s_sleep(1);
    } while (__all(v >= phase) == 0);
    if (tid == 0)
      __hip_atomic_store(&gflags[g], phase, __ATOMIC_RELAXED, __HIP_MEMORY_SCOPE_AGENT);
    if (bid == 0) {                            // root
      unsigned int gv;
      do {
        gv = __hip_atomic_load(&gflags[tid & 7], __ATOMIC_RELAXED, __HIP_MEMORY_SCOPE_AGENT);
        if (gv < phase) __builtin_amdgcn_s_sleep(1);
      } while (__all(gv >= phase) == 0);
      if (tid == 0)
        __hip_atomic_store(gen, phase, __ATOMIC_RELAXED, __HIP_MEMORY_SCOPE_AGENT);
    }
  }
  if (tid == 0) {
    while (__hip_atomic_load(gen, __ATOMIC_RELAXED, __HIP_MEMORY_SCOPE_AGENT) < phase)
      __builtin_amdgcn_s_sleep(1);
  }
  asm volatile("" ::: "memory");       // no load hoisting above the poll
  __syncthreads();
}

__global__ void zero_bar(unsigned int* bar) {
  int i = blockIdx.x * 256 + threadIdx.x;
  if (i < 1024) bar[i] = 0u;
}

// ---------------- prep kernels ----------------

// ebf[m=t*64+b][k] = bf16(emb[x[b][t]][k])
__global__ void prep_e(const int* __restrict__ x, const float* __restrict__ emb,
                       unsigned short* __restrict__ ebf) {
  int idx = blockIdx.x * 256 + threadIdx.x;   // [0, 8192*32)
  int koct = idx & 31;
  int m = idx >> 5;
  int t = m >> 6, b = m & 63;
  int tok = x[b * 128 + t];
  const float* src = emb + (size_t)tok * 256 + (size_t)koct * 8;
  short8 v;
#pragma unroll
  for (int j = 0; j < 8; ++j) v[j] = (short)f2bf(src[j]);
  *(short8*)(ebf + (size_t)m * 256 + koct * 8) = v;
}

// Wt[n][k] = bf16(W[k][n]); W is [K][4096]
__global__ void prep_wt(const float* __restrict__ W, unsigned short* __restrict__ Wt, int K) {
  int idx = blockIdx.x * 256 + threadIdx.x;   // [0, 4096*(K/8))
  int n = idx & 4095;
  int koct = idx >> 12;
  short8 v;
#pragma unroll
  for (int j = 0; j < 8; ++j) v[j] = (short)f2bf(W[(size_t)(koct * 8 + j) * 4096 + n]);
  *(short8*)(Wt + (size_t)n * K + koct * 8) = v;
}

__global__ void prep_cvt(const float* __restrict__ s, unsigned short* __restrict__ d) {
  int i = blockIdx.x * 256 + threadIdx.x;
  d[i] = f2bf(s[i]);
}

// ---------------- fused two-layer LSTM (one cooperative dispatch) ----------------
// Block bid owns j-quad = bid*4..bid*4+3 for BOTH layers. Super-step s:
//   layer-1: y1[s] from e[s] + h1 (slab s);  layer-2: out[s-1] from y1[s-1]
//   (= slab s, SAME loads) + h2 (slab s-1). 128 barriers total.
// K-SPLIT x2 -> 512 threads, 8 waves, 2 waves/SIMD. Waves 0-3 (kg=0) reduce
// ks 0..15, waves 4-7 (kg=1) ks 16..31; partial gate sums combine via an 8 KB
// LDS buffer (transposed layout, conflict-free ds_write_b32) + one
// __syncthreads. TLP=2 hides the LLC load latency that dominated at
// 1 wave/SIMD (MfmaUtil 6.2%). No sched_barrier pinning, no cross-barrier
// prefetch (implicated in the R2 numerical failure); load style and the
// hierarchical barrier are exactly the R0-proven ones.
__global__ __launch_bounds__(512, 2) void lstm_fused(
    const unsigned short* __restrict__ W1t,  // [4096][256]  bf16
    const unsigned short* __restrict__ U1t,  // [4096][1024] bf16
    const unsigned short* __restrict__ W2t,  // [4096][1024] bf16
    const unsigned short* __restrict__ U2t,  // [4096][1024] bf16
    const unsigned short* __restrict__ ebf,  // [8192][256]  bf16
    unsigned short* __restrict__ h1h,        // [129][64][1024], slab 0 prefilled
    unsigned short* __restrict__ h2h,        // [129][64][1024], slab 0 prefilled
    const float* __restrict__ c0_1, const float* __restrict__ c0_2,
    const float* __restrict__ b1,   const float* __restrict__ b2,
    float* __restrict__ outy,                 // [64][128][1024]
    float* __restrict__ hT1, float* __restrict__ cT1,
    float* __restrict__ hT2, float* __restrict__ cT2,
    unsigned int* __restrict__ bar) {
  extern __shared__ __align__(16) unsigned short lds[];   // 112 KB total
  unsigned short* U1l = lds;             // 32 KB
  unsigned short* W2l = lds + 16384;     // 32 KB
  unsigned short* U2l = lds + 32768;     // 32 KB
  unsigned short* W1l = lds + 49152;     // 8 KB (bytes 98304..106496)
  float* red = (float*)(lds + 53248);    // 8 KB: [8][256] f32, transposed (bank-clean)
  const int bid = blockIdx.x, tid = threadIdx.x;
  const int w = tid >> 6, l = tid & 63;
  const int kg = w >> 2;                 // K-group: 0 -> ks 0..15, 1 -> ks 16..31
  const int bw = w & 3;                  // b-tile within K-group

  // stage A-fragments from n-major bf16 arrays; each wave reads full 64B lines
  for (int run = tid; run < 2048; run += 512) {
    int ll = run & 63, ks = run >> 6;
    int m = ll & 15;
    int n = (m & 3) * 1024 + bid * 4 + (m >> 2);
    int kb = ks * 32 + (ll >> 4) * 8;
    *(short8*)&U1l[run * 8] = *(const short8*)&U1t[(size_t)n * 1024 + kb];
    *(short8*)&W2l[run * 8] = *(const short8*)&W2t[(size_t)n * 1024 + kb];
    *(short8*)&U2l[run * 8] = *(const short8*)&U2t[(size_t)n * 1024 + kb];
  }
  for (int run = tid; run < 512; run += 512) {
    int ll = run & 63, ks = run >> 6;
    int m = ll & 15;
    int n = (m & 3) * 1024 + bid * 4 + (m >> 2);
    int kb = ks * 32 + (ll >> 4) * 8;
    *(short8*)&W1l[run * 8] = *(const short8*)&W1t[(size_t)n * 256 + kb];
  }
  __syncthreads();

  const int b = bw * 16 + (l & 15);
  const int jj = l >> 4;
  const int j = bid * 4 + jj;
  const int kq = jj * 8;
  const int ksBeg = kg * 16;             // this wave's half of the 32 ks-steps
  const int kBeg = kg * 4;               // this wave's half of the 8 W1 k-steps
  const int ridx = bw * 64 + l;          // reduce slot, shared by kg0/kg1 partners
  float c1 = c0_1[b * 1024 + j];
  float c2 = c0_2[b * 1024 + j];
  float b1r[4], b2r[4];
#pragma unroll
  for (int g = 0; g < 4; ++g) { b1r[g] = b1[g * 1024 + j]; b2r[g] = b2[g * 1024 + j]; }

  // ---- s = 0: layer-1 only ----
  {
    const unsigned short* er = ebf + ((size_t)b << 8);        // t=0 row
    const unsigned short* h1row = h1h + (size_t)b * 1024;     // slab 0
    short8 ev[4], h1v[16];
#pragma unroll
    for (int i = 0; i < 4; ++i) ev[i] = *(const short8*)&er[(kBeg + i) * 32 + kq];
#pragma unroll
    for (int i = 0; i < 16; ++i) h1v[i] = *(const short8*)&h1row[(ksBeg + i) * 32 + kq];
    floatx4 a1a = {0.f, 0.f, 0.f, 0.f}, a1b = a1a;
#pragma unroll
    for (int i = 0; i < 4; ++i) {
      short8 w1 = *(const short8*)&W1l[((kBeg + i) * 64 + l) * 8];
      if (i & 1) a1b = MFMA16(w1, ev[i], a1b); else a1a = MFMA16(w1, ev[i], a1a);
    }
#pragma unroll
    for (int i = 0; i < 16; ++i) {
      short8 u1 = *(const short8*)&U1l[((ksBeg + i) * 64 + l) * 8];
      if (i & 1) a1b = MFMA16(u1, h1v[i], a1b); else a1a = MFMA16(u1, h1v[i], a1a);
    }
    floatx4 z1p = a1a + a1b;
    if (kg) {
#pragma unroll
      for (int i = 0; i < 4; ++i) red[i * 256 + ridx] = z1p[i];
    }
    __syncthreads();
    if (!kg) {
      floatx4 z1 = z1p;
#pragma unroll
      for (int i = 0; i < 4; ++i) z1[i] += red[i * 256 + ridx];
      float ig = sigm(z1[0] + b1r[0]), fg = sigm(z1[1] + b1r[1]);
      float gg = tanh_f(z1[2] + b1r[2]), og = sigm(z1[3] + b1r[3]);
      c1 = fg * c1 + ig * gg;
      float h = og * tanh_f(c1);
      llc_store_u16(h1h + 65536 + (size_t)b * 1024 + j, f2bf(h));
    }
    gridbar(bar, 1u);
  }

  // ---- s = 1..127: both layers ----
  for (int s = 1; s < 128; ++s) {
    const unsigned short* er = ebf + ((size_t)(s * 64 + b) << 8);
    const unsigned short* h1row = h1h + (size_t)s * 65536 + (size_t)b * 1024;
    const unsigned short* h2row = h2h + (size_t)(s - 1) * 65536 + (size_t)b * 1024;
    short8 ev[4], h1v[16], h2v[16];
#pragma unroll
    for (int i = 0; i < 16; ++i) h1v[i] = *(const short8*)&h1row[(ksBeg + i) * 32 + kq];
#pragma unroll
    for (int i = 0; i < 16; ++i) h2v[i] = *(const short8*)&h2row[(ksBeg + i) * 32 + kq];
#pragma unroll
    for (int i = 0; i < 4; ++i) ev[i] = *(const short8*)&er[(kBeg + i) * 32 + kq];

    floatx4 a1a = {0.f, 0.f, 0.f, 0.f}, a1b = a1a;
    floatx4 a2a = a1a, a2b = a1a, a2c = a1a, a2d = a1a;
#pragma unroll
    for (int i = 0; i < 4; ++i) {
      short8 w1 = *(const short8*)&W1l[((kBeg + i) * 64 + l) * 8];
      if (i & 1) a1b = MFMA16(w1, ev[i], a1b); else a1a = MFMA16(w1, ev[i], a1a);
    }
#pragma unroll
    for (int i = 0; i < 16; ++i) {
      short8 u1 = *(const short8*)&U1l[((ksBeg + i) * 64 + l) * 8];
      short8 w2 = *(const short8*)&W2l[((ksBeg + i) * 64 + l) * 8];
      short8 u2 = *(const short8*)&U2l[((ksBeg + i) * 64 + l) * 8];
      if (i & 1) {
        a1b = MFMA16(u1, h1v[i], a1b);
        a2b = MFMA16(w2, h1v[i], a2b);
        a2d = MFMA16(u2, h2v[i], a2d);
      } else {
        a1a = MFMA16(u1, h1v[i], a1a);
        a2a = MFMA16(w2, h1v[i], a2a);
        a2c = MFMA16(u2, h2v[i], a2c);
      }
    }
    floatx4 z1p = a1a + a1b, z2p = (a2a + a2b) + (a2c + a2d);
    if (kg) {
#pragma unroll
      for (int i = 0; i < 4; ++i) red[i * 256 + ridx] = z1p[i];
#pragma unroll
      for (int i = 0; i < 4; ++i) red[(i + 4) * 256 + ridx] = z2p[i];
    }
    __syncthreads();
    if (!kg) {
      floatx4 z1 = z1p, z2 = z2p;
#pragma unroll
      for (int i = 0; i < 4; ++i) z1[i] += red[i * 256 + ridx];
#pragma unroll
      for (int i = 0; i < 4; ++i) z2[i] += red[(i + 4) * 256 + ridx];
      {
        float ig = sigm(z1[0] + b1r[0]), fg = sigm(z1[1] + b1r[1]);
        float gg = tanh_f(z1[2] + b1r[2]), og = sigm(z1[3] + b1r[3]);
        c1 = fg * c1 + ig * gg;
        float h = og * tanh_f(c1);
        llc_store_u16(h1h + (size_t)(s + 1) * 65536 + (size_t)b * 1024 + j, f2bf(h));
        if (s == 127) { hT1[b * 1024 + j] = h; cT1[b * 1024 + j] = c1; }
      }
      {
        float ig = sigm(z2[0] + b2r[0]), fg = sigm(z2[1] + b2r[1]);
        float gg = tanh_f(z2[2] + b2r[2]), og = sigm(z2[3] + b2r[3]);
        c2 = fg * c2 + ig * gg;
        float h = og * tanh_f(c2);
        llc_store_u16(h2h + (size_t)s * 65536 + (size_t)b * 1024 + j, f2bf(h));
        outy[(size_t)b * 131072 + (size_t)(s - 1) * 1024 + j] = h;
      }
    }
    gridbar(bar, (unsigned int)(s + 1));
  }

  // ---- s = 128: layer-2 only ----
  {
    const unsigned short* h1row = h1h + (size_t)128 * 65536 + (size_t)b * 1024;
    const unsigned short* h2row = h2h + (size_t)127 * 65536 + (size_t)b * 1024;
    short8 h1v[16], h2v[16];
#pragma unroll
    for (int i = 0; i < 16; ++i) h1v[i] = *(const short8*)&h1row[(ksBeg + i) * 32 + kq];
#pragma unroll
    for (int i = 0; i < 16; ++i) h2v[i] = *(const short8*)&h2row[(ksBeg + i) * 32 + kq];
    floatx4 a2a = {0.f, 0.f, 0.f, 0.f}, a2b = a2a, a2c = a2a, a2d = a2a;
#pragma unroll
    for (int i = 0; i < 16; ++i) {
      short8 w2 = *(const short8*)&W2l[((ksBeg + i) * 64 + l) * 8];
      short8 u2 = *(const short8*)&U2l[((ksBeg + i) * 64 + l) * 8];
      if (i & 1) { a2b = MFMA16(w2, h1v[i], a2b); a2d = MFMA16(u2, h2v[i], a2d); }
      else        { a2a = MFMA16(w2, h1v[i], a2a); a2c = MFMA16(u2, h2v[i], a2c); }
    }
    floatx4 z2p = (a2a + a2b) + (a2c + a2d);
    if (kg) {
#pragma unroll
      for (int i = 0; i < 4; ++i) red[i * 256 + ridx] = z2p[i];
    }
    __syncthreads();
    if (!kg) {
      floatx4 z2 = z2p;
#pragma unroll
      for (int i = 0; i < 4; ++i) z2[i] += red[i * 256 + ridx];
      float ig = sigm(z2[0] + b2r[0]), fg = sigm(z2[1] + b2r[1]);
      float gg = tanh_f(z2[2] + b2r[2]), og = sigm(z2[3] + b2r[3]);
      c2 = fg * c2 + ig * gg;
      float h = og * tanh_f(c2);
      outy[(size_t)b * 131072 + (size_t)127 * 1024 + j] = h;
      hT2[b * 1024 + j] = h;
      cT2[b * 1024 + j] = c2;
    }
  }
}

// ---------------- launch ----------------
extern "C" void kernel_launch(void* const* d_in, const int* in_sizes, int n_in,
                              void* d_out, int out_size, void* d_ws, size_t ws_size,
                              hipStream_t stream) {
  const int*   x    = (const int*)d_in[0];
  const float* h0_1 = (const float*)d_in[1];
  const float* c0_1 = (const float*)d_in[2];
  const float* h0_2 = (const float*)d_in[3];
  const float* c0_2 = (const float*)d_in[4];
  const float* emb  = (const float*)d_in[5];
  const float* W1   = (const float*)d_in[6];
  const float* U1   = (const float*)d_in[7];
  const float* b1   = (const float*)d_in[8];
  const float* W2   = (const float*)d_in[9];
  const float* U2   = (const float*)d_in[10];
  const float* b2   = (const float*)d_in[11];
  float* outf = (float*)d_out;

  unsigned short* ws  = (unsigned short*)d_ws;
  unsigned short* ebf = ws;                    //  2,097,152 ush
  unsigned short* W1t = ws +  2097152;         //  1,048,576
  unsigned short* U1t = ws +  3145728;         //  4,194,304
  unsigned short* W2t = ws +  7340032;         //  4,194,304
  unsigned short* U2t = ws + 11534336;         //  4,194,304
  unsigned short* h1h = ws + 15728640;         //  8,454,144
  unsigned short* h2h = ws + 24182784;         //  8,454,144
  unsigned int*   bar = (unsigned int*)(ws + 32636928);  // 4 KB (total ~65.3 MB)

  float* hT1 = outf + 8388608;
  float* cT1 = outf + 8454144;
  float* hT2 = outf + 8519680;
  float* cT2 = outf + 8585216;

  zero_bar<<<4, 256, 0, stream>>>(bar);
  prep_e<<<1024, 256, 0, stream>>>(x, emb, ebf);
  prep_wt<<<512,  256, 0, stream>>>(W1, W1t, 256);
  prep_wt<<<2048, 256, 0, stream>>>(U1, U1t, 1024);
  prep_wt<<<2048, 256, 0, stream>>>(W2, W2t, 1024);
  prep_wt<<<2048, 256, 0, stream>>>(U2, U2t, 1024);
  prep_cvt<<<256, 256, 0, stream>>>(h0_1, h1h);
  prep_cvt<<<256, 256, 0, stream>>>(h0_2, h2h);

  // allow 112 KB dynamic LDS (gfx950 has 160 KB/CU)
  static bool attr_done = false;
  if (!attr_done) {
    (void)hipFuncSetAttribute((const void*)lstm_fused,
                              hipFuncAttributeMaxDynamicSharedMemorySize, 114688);
    attr_done = true;
  }

  {
    const unsigned short *w1c = W1t, *u1c = U1t, *w2c = W2t, *u2c = U2t, *ec = ebf;
    unsigned short *h1c = h1h, *h2c = h2h;
    const float *c01 = c0_1, *c02 = c0_2, *b1c = b1, *b2c = b2;
    float *oy = outf, *ht1 = hT1, *ct1 = cT1, *ht2 = hT2, *ct2 = cT2;
    unsigned int* brc = bar;
    void* args[] = {&w1c, &u1c, &w2c, &u2c, &ec, &h1c, &h2c,
                    &c01, &c02, &b1c, &b2c, &oy, &ht1, &ct1, &ht2, &ct2, &brc};
    hipError_t e = hipLaunchCooperativeKernel((void*)lstm_fused, dim3(256), dim3(512),
                                              args, 114688, stream);
    if (e != hipSuccess) {
      // Defensive fallback: 256 blocks x 112 KB LDS = 1 block/CU on 256 CUs,
      // so all blocks are co-resident under a plain launch too; the gridbar
      // remains safe. Avoids silent no-op if the cooperative capacity check
      // rejects the 512-thread configuration.
      lstm_fused<<<dim3(256), dim3(512), 114688, stream>>>(
          w1c, u1c, w2c, u2c, ec, h1c, h2c, c01, c02, b1c, b2c,
          oy, ht1, ct1, ht2, ct2, brc);
    }
  }
}